// Round 5
// baseline (776.569 us; speedup 1.0000x reference)
//
#include <hip/hip_runtime.h>

// Problem constants
#define Bb 16
#define Nn_ 576
#define Cc 1024
#define Hh 16
#define HD 64
#define HID 4096
#define AVAIL 832   // CUR(256) + N(576)
#define ROWS (Bb*Nn_)  // 9216

typedef __bf16 bf16x8 __attribute__((ext_vector_type(8)));
typedef float f32x4 __attribute__((ext_vector_type(4)));

__device__ __forceinline__ unsigned short f2bf(float f) {
  unsigned u = __float_as_uint(f);
  u += 0x7FFF + ((u >> 16) & 1);
  return (unsigned short)(u >> 16);
}

__device__ __forceinline__ void glds16(const void* g, void* l) {
  __builtin_amdgcn_global_load_lds(
      (const __attribute__((address_space(1))) void*)g,
      (__attribute__((address_space(3))) void*)l, 16, 0, 0);
}

#define BARR() asm volatile("s_barrier" ::: "memory")
#define VMCNT4() asm volatile("s_waitcnt vmcnt(4)" ::: "memory")
#define VMCNT0() asm volatile("s_waitcnt vmcnt(0)" ::: "memory")
#define LGKM0() asm volatile("s_waitcnt lgkmcnt(0)" ::: "memory")

// ---------------- weight convert + transpose: in [K][N] f32 -> out [N][K] bf16
__global__ void wtrans_k(const float* __restrict__ in, unsigned short* __restrict__ out,
                         int K, int N) {
  __shared__ float tile[32][33];
  int k0 = blockIdx.x * 32, n0 = blockIdx.y * 32;
  int tx = threadIdx.x, ty = threadIdx.y;  // 32 x 8
#pragma unroll
  for (int i = 0; i < 4; i++)
    tile[ty + i * 8][tx] = in[(size_t)(k0 + ty + i * 8) * N + n0 + tx];
  __syncthreads();
#pragma unroll
  for (int i = 0; i < 4; i++)
    out[(size_t)(n0 + ty + i * 8) * K + k0 + tx] = f2bf(tile[tx][ty + i * 8]);
}

// ---------------- LayerNorm f32 -> bf16, one block per row of 1024
__global__ void ln_k(const float* __restrict__ x, const float* __restrict__ w,
                     const float* __restrict__ bi, unsigned short* __restrict__ out) {
  int row = blockIdx.x;
  int t = threadIdx.x;
  float4 v = ((const float4*)(x + (size_t)row * Cc))[t];
  float s = v.x + v.y + v.z + v.w;
  float s2 = v.x * v.x + v.y * v.y + v.z * v.z + v.w * v.w;
#pragma unroll
  for (int off = 1; off < 64; off <<= 1) { s += __shfl_xor(s, off); s2 += __shfl_xor(s2, off); }
  __shared__ float red[8];
  int wid = t >> 6, lane = t & 63;
  if (lane == 0) { red[wid] = s; red[4 + wid] = s2; }
  __syncthreads();
  s = red[0] + red[1] + red[2] + red[3];
  s2 = red[4] + red[5] + red[6] + red[7];
  float mean = s * (1.0f / Cc);
  float var = s2 * (1.0f / Cc) - mean * mean;
  float rstd = rsqrtf(var + 1e-5f);
  float4 wv = ((const float4*)w)[t];
  float4 bv = ((const float4*)bi)[t];
  ushort4 ov;
  ov.x = f2bf((v.x - mean) * rstd * wv.x + bv.x);
  ov.y = f2bf((v.y - mean) * rstd * wv.y + bv.y);
  ov.z = f2bf((v.z - mean) * rstd * wv.z + bv.z);
  ov.w = f2bf((v.w - mean) * rstd * wv.w + bv.w);
  *(ushort4*)(out + (size_t)row * Cc + t * 4) = ov;
}

// ---------------- init: out[row][col] = resid[row][col] + bias[col]  (f32)
__global__ void initout_k(const float* __restrict__ resid, const float* __restrict__ bias,
                          float* __restrict__ out) {
  int row = blockIdx.x, t = threadIdx.x;
  float4 r = ((const float4*)(resid + (size_t)row * Cc))[t];
  float4 bv = ((const float4*)bias)[t];
  r.x += bv.x; r.y += bv.y; r.z += bv.z; r.w += bv.w;
  ((float4*)(out + (size_t)row * Cc))[t] = r;
}

// ---------------- 256x256 8-wave pipelined GEMM, BK=64, 128KB LDS dbuf.
// C[M][N] = A[M][K](bf16) @ Bt[N][K]^T (bf16) + bias
// EPI: 0 bf16, 1 gelu->bf16, 2 f32+resid, 3 atomicAdd f32 (no bias; split-K)
// Per-phase ds_read distribution 12/4/8/0 (per-quadrant) so LDS service
// overlaps MFMA across phases; one counted vmcnt(4) per K-tile.
template <int EPI>
__global__ __launch_bounds__(512, 2) void gemm8_k(
    const unsigned short* __restrict__ A, const unsigned short* __restrict__ Bt,
    const float* __restrict__ bias, const float* __restrict__ resid,
    void* __restrict__ outv, int N, int K, int ksplit) {
  extern __shared__ __align__(16) char smem[];
  char* A0buf = smem;            // buf0 A tile (2 halves of 16KB)
  char* B0buf = smem + 32768;    // buf0 B tile
  char* A1buf = smem + 65536;    // buf1 A tile
  char* B1buf = smem + 98304;    // buf1 B tile

  const int tid = threadIdx.x, lane = tid & 63, wid = tid >> 6;
  const int wr = wid >> 2, wc = wid & 3;
  const int l15 = lane & 15, l4 = lane >> 4;
  const int m0 = blockIdx.x * 256, n0 = blockIdx.y * 256;
  const int KT = ksplit >> 6;
  const size_t K2 = (size_t)K * 2;
  const size_t kb2 = (size_t)blockIdx.z * ksplit * 2;

  // staging: thread covers row (tid>>3) of a 64-row stripe, 16B slot (tid&7)^((tid>>3)&7)
  const int toff = (tid >> 3) * (int)K2 + ((((tid & 7) ^ ((tid >> 3) & 7)) << 4));
  const char* As0 = (const char*)A + (size_t)m0 * K2 + toff + kb2;   // A rows m0..
  const char* As1 = As0 + 128 * K2;                                  // A rows m0+128..
  const char* Bs0 = (const char*)Bt + (size_t)n0 * K2 + toff + kb2;
  const char* Bs1 = Bs0 + 128 * K2;
  const size_t l64 = 64 * K2;
  const int dst = tid * 16;

  // read-side: swizzled 16B-slot offset for ks=0; ks=1 flips byte bit6
  const int s0 = ((l4 ^ (l15 & 7)) << 4);
  const int rbA = (wr * 128 + l15) * 128;
  const int rbB = (wc * 64 + l15) * 128;

  f32x4 acc[2][2][4][2] = {};  // [mh][nh][mi][ni]
  bf16x8 a0[4][2], a1[4][2], bb0[2][2], bb1[2][2];

#define STAGE(srcH, ktb, ldsT, half)                        \
  do {                                                      \
    const char* _g = (srcH) + (size_t)(ktb);                \
    glds16(_g, (ldsT) + (half) * 16384 + dst);              \
    glds16(_g + l64, (ldsT) + (half) * 16384 + 8192 + dst); \
  } while (0)

#define RD_A(dA, CA, mh)                                                           \
  _Pragma("unroll") for (int mi = 0; mi < 4; ++mi)                                 \
  _Pragma("unroll") for (int ks = 0; ks < 2; ++ks)                                 \
    dA[mi][ks] = *(const bf16x8*)((CA) + rbA + (mh) * 8192 + mi * 2048 + (s0 ^ (ks << 6)));

#define RD_B(dB, CB, nh)                                                           \
  _Pragma("unroll") for (int ni = 0; ni < 2; ++ni)                                 \
  _Pragma("unroll") for (int ks = 0; ks < 2; ++ks)                                 \
    dB[ni][ks] = *(const bf16x8*)((CB) + rbB + (nh) * 4096 + ni * 2048 + (s0 ^ (ks << 6)));

#define MF(mh, nh, av, bv)                                                         \
  _Pragma("unroll") for (int mi = 0; mi < 4; ++mi)                                 \
  _Pragma("unroll") for (int ni = 0; ni < 2; ++ni)                                 \
  _Pragma("unroll") for (int ks = 0; ks < 2; ++ks)                                 \
    acc[mh][nh][mi][ni] = __builtin_amdgcn_mfma_f32_16x16x32_bf16(                 \
        av[mi][ks], bv[ni][ks], acc[mh][nh][mi][ni], 0, 0, 0);

// Steady-state K-tile, reads balanced per quadrant (12/4/8/0):
//  P1: rd a0+bb0, stage t+1.h1(A);  c0 = a0*bb0
//  P2: rd bb1,    stage t+1.h1(B);  c1 = a0*bb1
//  P3: rd a1, lgkmcnt(0) [all CUR-buffer reads done -> safe to overwrite h0]; c2
//  P4: stage t+2.h0(A,B) into CUR; vmcnt(4) [t+1 fully landed]; c3
#define TILE(CA, CB, OA, OB, t)                                     \
  do {                                                              \
    const size_t kt1 = (size_t)((t) + 1) * 128;                     \
    const size_t kt2 = (size_t)((t) + 2) * 128;                     \
    /* P1 */                                                        \
    RD_A(a0, CA, 0); RD_B(bb0, CB, 0);                              \
    STAGE(As1, kt1, OA, 1);                                         \
    BARR();                                                         \
    __builtin_amdgcn_s_setprio(1); MF(0, 0, a0, bb0);               \
    __builtin_amdgcn_s_setprio(0); BARR();                          \
    /* P2 */                                                        \
    RD_B(bb1, CB, 1);                                               \
    STAGE(Bs1, kt1, OB, 1);                                         \
    BARR();                                                         \
    __builtin_amdgcn_s_setprio(1); MF(0, 1, a0, bb1);               \
    __builtin_amdgcn_s_setprio(0); BARR();                          \
    /* P3 */                                                        \
    RD_A(a1, CA, 1);                                                \
    LGKM0(); BARR();                                                \
    __builtin_amdgcn_s_setprio(1); MF(1, 0, a1, bb0);               \
    __builtin_amdgcn_s_setprio(0); BARR();                          \
    /* P4 */                                                        \
    STAGE(As0, kt2, CA, 0);                                         \
    STAGE(Bs0, kt2, CB, 0);                                         \
    VMCNT4(); BARR();                                               \
    __builtin_amdgcn_s_setprio(1); MF(1, 1, a1, bb1);               \
    __builtin_amdgcn_s_setprio(0); BARR();                          \
  } while (0)

// Tile KT-2: stage only tile KT-1 half1; drain ALL loads at P4.
#define TILE_T1(CA, CB, OA, OB, t)                                  \
  do {                                                              \
    const size_t kt1 = (size_t)((t) + 1) * 128;                     \
    RD_A(a0, CA, 0); RD_B(bb0, CB, 0);                              \
    STAGE(As1, kt1, OA, 1);                                         \
    BARR();                                                         \
    __builtin_amdgcn_s_setprio(1); MF(0, 0, a0, bb0);               \
    __builtin_amdgcn_s_setprio(0); BARR();                          \
    RD_B(bb1, CB, 1);                                               \
    STAGE(Bs1, kt1, OB, 1);                                         \
    BARR();                                                         \
    __builtin_amdgcn_s_setprio(1); MF(0, 1, a0, bb1);               \
    __builtin_amdgcn_s_setprio(0); BARR();                          \
    RD_A(a1, CA, 1);                                                \
    LGKM0(); BARR();                                                \
    __builtin_amdgcn_s_setprio(1); MF(1, 0, a1, bb0);               \
    __builtin_amdgcn_s_setprio(0); BARR();                          \
    VMCNT0(); BARR();                                               \
    __builtin_amdgcn_s_setprio(1); MF(1, 1, a1, bb1);               \
    __builtin_amdgcn_s_setprio(0); BARR();                          \
  } while (0)

// Tile KT-1: pure compute.
#define TILE_T2(CA, CB)                                             \
  do {                                                              \
    RD_A(a0, CA, 0); RD_A(a1, CA, 1); RD_B(bb0, CB, 0); RD_B(bb1, CB, 1); \
    MF(0, 0, a0, bb0); MF(0, 1, a0, bb1);                           \
    MF(1, 0, a1, bb0); MF(1, 1, a1, bb1);                           \
  } while (0)

  // prologue: stage tile0 (4 halves) + tile1 half0
  STAGE(As0, 0, A0buf, 0);
  STAGE(Bs0, 0, B0buf, 0);
  STAGE(As1, 0, A0buf, 1);
  STAGE(Bs1, 0, B0buf, 1);
  STAGE(As0, 128, A1buf, 0);
  STAGE(Bs0, 128, B1buf, 0);
  VMCNT4();
  BARR();

#pragma unroll 1
  for (int t = 0; t + 3 < KT; t += 2) {
    TILE(A0buf, B0buf, A1buf, B1buf, t);
    TILE(A1buf, B1buf, A0buf, B0buf, t + 1);
  }
  TILE_T1(A0buf, B0buf, A1buf, B1buf, KT - 2);
  TILE_T2(A1buf, B1buf);

  // epilogue
#pragma unroll
  for (int mh = 0; mh < 2; mh++)
#pragma unroll
    for (int nh = 0; nh < 2; nh++)
#pragma unroll
      for (int ni = 0; ni < 2; ni++) {
        int col = n0 + wc * 64 + nh * 32 + ni * 16 + l15;
        float bv = (EPI == 3) ? 0.f : bias[col];
#pragma unroll
        for (int mi = 0; mi < 4; mi++) {
          int rbase = m0 + wr * 128 + mh * 64 + mi * 16 + l4 * 4;
#pragma unroll
          for (int j = 0; j < 4; j++) {
            size_t idx = (size_t)(rbase + j) * N + col;
            float v = acc[mh][nh][mi][ni][j] + bv;
            if (EPI == 1) v = 0.5f * v * (1.0f + erff(v * 0.70710678118f));
            if (EPI == 3)
              atomicAdd(&((float*)outv)[idx], v);
            else if (EPI == 2)
              ((float*)outv)[idx] = v + resid[idx];
            else
              ((unsigned short*)outv)[idx] = f2bf(v);
          }
        }
      }
#undef TILE_T2
#undef TILE_T1
#undef TILE
#undef MF
#undef RD_B
#undef RD_A
#undef STAGE
}

// ---------------- gather K: Kg[bh][p][d] (bf16) from qkv + cache_k
__global__ void gatherk_k(const unsigned short* __restrict__ qkv,
                          const float* __restrict__ cache_k,
                          unsigned short* __restrict__ Kg) {
  int bh = blockIdx.y, b = bh >> 4, h = bh & 15;
  int p = blockIdx.x * 4 + (threadIdx.x >> 6);
  int d = threadIdx.x & 63;
  unsigned short val;
  if (p < 64)
    val = qkv[((size_t)(b * Nn_ + p)) * 3072 + 1024 + h * 64 + d];
  else if (p < 320)
    val = f2bf(cache_k[(((size_t)b * Hh + h) * 1024 + p) * 64 + d]);
  else
    val = qkv[((size_t)(b * Nn_ + p - 256)) * 3072 + 1024 + h * 64 + d];
  Kg[(((size_t)bh) * AVAIL + p) * 64 + d] = val;
}

// ---------------- gather V transposed: Vt[bh][d][p] (bf16)
__global__ void gathervt_k(const unsigned short* __restrict__ qkv,
                           const float* __restrict__ cache_v,
                           unsigned short* __restrict__ Vt) {
  __shared__ float tile[32][33];
  int bh = blockIdx.z, b = bh >> 4, h = bh & 15;
  int p0 = blockIdx.x * 32, d0 = blockIdx.y * 32;
  int tx = threadIdx.x, ty = threadIdx.y;  // 32 x 8
#pragma unroll
  for (int i = 0; i < 4; i++) {
    int p = p0 + ty + i * 8, d = d0 + tx;
    float v;
    if (p < 64)
      v = __uint_as_float((unsigned)qkv[((size_t)(b * Nn_ + p)) * 3072 + 2048 + h * 64 + d] << 16);
    else if (p < 320)
      v = cache_v[(((size_t)b * Hh + h) * 1024 + p) * 64 + d];
    else
      v = __uint_as_float((unsigned)qkv[((size_t)(b * Nn_ + p - 256)) * 3072 + 2048 + h * 64 + d] << 16);
    tile[ty + i * 8][tx] = v;
  }
  __syncthreads();
#pragma unroll
  for (int i = 0; i < 4; i++)
    Vt[(((size_t)bh) * 64 + d0 + ty + i * 8) * AVAIL + p0 + tx] = f2bf(tile[tx][ty + i * 8]);
}

// ---------------- flash attention: block = (qtile, bh); 4 waves x 16 q-rows
__global__ __launch_bounds__(256) void attn_k(
    const unsigned short* __restrict__ qkv, const unsigned short* __restrict__ Kg,
    const unsigned short* __restrict__ Vt, unsigned short* __restrict__ o) {
  __shared__ __attribute__((aligned(16))) unsigned short Qs[64 * 64];
  __shared__ __attribute__((aligned(16))) unsigned short Ks[64 * 64];
  __shared__ __attribute__((aligned(16))) unsigned short Vs[64 * 64];
  __shared__ __attribute__((aligned(16))) unsigned short Ps[4][16 * 64];

  const int tid = threadIdx.x;
  const int lane = tid & 63;
  const int w = tid >> 6;
  const int qt = blockIdx.x;
  const int bh = blockIdx.y, b = bh >> 4, h = bh & 15;
  const float scale = 0.125f;

  {
    int r = tid >> 3;
    int cb = (tid & 7) << 4;
    const char* qb = (const char*)qkv;
    glds16(qb + ((size_t)(b * Nn_ + qt * 64 + r) * 3072 + h * 64) * 2 + cb, (char*)Qs + tid * 16);
    glds16(qb + ((size_t)(b * Nn_ + qt * 64 + 32 + r) * 3072 + h * 64) * 2 + cb,
           (char*)Qs + 4096 + tid * 16);
  }

  float m_run[4], l_run[4];
  f32x4 oacc[4] = {};
#pragma unroll
  for (int j = 0; j < 4; j++) { m_run[j] = -1e30f; l_run[j] = 0.f; }

  const char* kbase = (const char*)(Kg + (size_t)bh * AVAIL * 64);
  const char* vbase = (const char*)(Vt + (size_t)bh * 64 * AVAIL);

  for (int c = 0; c < 13; c++) {
    __syncthreads();
    glds16(kbase + (size_t)c * 8192 + tid * 16, (char*)Ks + tid * 16);
    glds16(kbase + (size_t)c * 8192 + 4096 + tid * 16, (char*)Ks + 4096 + tid * 16);
    {
      int r = tid >> 3;
      int cb = (tid & 7) << 4;
      glds16(vbase + (size_t)r * (AVAIL * 2) + c * 128 + cb, (char*)Vs + tid * 16);
      glds16(vbase + (size_t)(r + 32) * (AVAIL * 2) + c * 128 + cb, (char*)Vs + 4096 + tid * 16);
    }
    asm volatile("s_waitcnt vmcnt(0)" ::: "memory");
    __syncthreads();

    bf16x8 qf[2];
#pragma unroll
    for (int t = 0; t < 2; t++)
      qf[t] = *(const bf16x8*)&Qs[(w * 16 + (lane & 15)) * 64 + t * 32 + (lane >> 4) * 8];
    f32x4 s[4] = {};
#pragma unroll
    for (int nt = 0; nt < 4; nt++) {
#pragma unroll
      for (int t = 0; t < 2; t++) {
        bf16x8 kf = *(const bf16x8*)&Ks[(nt * 16 + (lane & 15)) * 64 + t * 32 + (lane >> 4) * 8];
        s[nt] = __builtin_amdgcn_mfma_f32_16x16x32_bf16(qf[t], kf, s[nt], 0, 0, 0);
      }
    }

    float p[4][4];
#pragma unroll
    for (int j = 0; j < 4; j++) {
      float mx = fmaxf(fmaxf(s[0][j], s[1][j]), fmaxf(s[2][j], s[3][j])) * scale;
#pragma unroll
      for (int off = 1; off < 16; off <<= 1) mx = fmaxf(mx, __shfl_xor(mx, off));
      float m_new = fmaxf(m_run[j], mx);
      float alpha = __expf(m_run[j] - m_new);
      float sum = 0.f;
#pragma unroll
      for (int nt = 0; nt < 4; nt++) {
        p[nt][j] = __expf(s[nt][j] * scale - m_new);
        sum += p[nt][j];
      }
#pragma unroll
      for (int off = 1; off < 16; off <<= 1) sum += __shfl_xor(sum, off);
      l_run[j] = l_run[j] * alpha + sum;
      m_run[j] = m_new;
#pragma unroll
      for (int nt2 = 0; nt2 < 4; nt2++) oacc[nt2][j] *= alpha;
    }

#pragma unroll
    for (int nt = 0; nt < 4; nt++)
#pragma unroll
      for (int j = 0; j < 4; j++)
        Ps[w][((lane >> 4) * 4 + j) * 64 + nt * 16 + (lane & 15)] = f2bf(p[nt][j]);

    bf16x8 pa[2];
#pragma unroll
    for (int t = 0; t < 2; t++)
      pa[t] = *(const bf16x8*)&Ps[w][(lane & 15) * 64 + t * 32 + (lane >> 4) * 8];
#pragma unroll
    for (int nt2 = 0; nt2 < 4; nt2++) {
#pragma unroll
      for (int t = 0; t < 2; t++) {
        bf16x8 vf = *(const bf16x8*)&Vs[(nt2 * 16 + (lane & 15)) * 64 + t * 32 + (lane >> 4) * 8];
        oacc[nt2] = __builtin_amdgcn_mfma_f32_16x16x32_bf16(pa[t], vf, oacc[nt2], 0, 0, 0);
      }
    }
  }

#pragma unroll
  for (int nt2 = 0; nt2 < 4; nt2++) {
#pragma unroll
    for (int j = 0; j < 4; j++) {
      int q = qt * 64 + w * 16 + (lane >> 4) * 4 + j;
      float v = oacc[nt2][j] / l_run[j];
      o[((size_t)(b * Nn_ + q)) * Cc + h * 64 + nt2 * 16 + (lane & 15)] = f2bf(v);
    }
  }
}

extern "C" void kernel_launch(void* const* d_in, const int* in_sizes, int n_in,
                              void* d_out, int out_size, void* d_ws, size_t ws_size,
                              hipStream_t stream) {
  const float* x = (const float*)d_in[0];
  const float* cache_k = (const float*)d_in[1];
  const float* cache_v = (const float*)d_in[2];
  const float* qkv_w = (const float*)d_in[3];
  const float* qkv_b = (const float*)d_in[4];
  const float* proj_w = (const float*)d_in[5];
  const float* proj_b = (const float*)d_in[6];
  const float* n1w = (const float*)d_in[7];
  const float* n1b = (const float*)d_in[8];
  const float* n2w = (const float*)d_in[9];
  const float* n2b = (const float*)d_in[10];
  const float* fc1w = (const float*)d_in[11];
  const float* fc1b = (const float*)d_in[12];
  const float* fc2w = (const float*)d_in[13];
  const float* fc2b = (const float*)d_in[14];

  char* ws = (char*)d_ws;
  unsigned short* wq_t = (unsigned short*)(ws + 0);          //  [3072][1024]
  unsigned short* wp_t = (unsigned short*)(ws + 6291456);    //  [1024][1024]
  unsigned short* w1_t = (unsigned short*)(ws + 8388608);    //  [4096][1024]
  unsigned short* w2_t = (unsigned short*)(ws + 16777216);   //  [1024][4096]
  float* x2           = (float*)(ws + 25165824);             //  [9216][1024] f32
  unsigned short* obuf = (unsigned short*)(ws + 62914560);   //  [9216][1024]
  unsigned short* hbuf = (unsigned short*)(ws + 81788928);   //  [9216][1024]
  unsigned short* vt   = (unsigned short*)(ws + 100663296);  //  [256][64][832]
  unsigned short* qkvb = (unsigned short*)(ws + 127926272);  //  [9216][3072]
  unsigned short* kg   = (unsigned short*)(ws + 184549376);  //  [256][832][64]
  unsigned short* midb = qkvb;  // fc1 out [9216][4096]; overruns into kg (dead by then)

  // allow 128KB dynamic LDS for gemm8 instantiations
  hipFuncSetAttribute((const void*)&gemm8_k<0>, hipFuncAttributeMaxDynamicSharedMemorySize, 131072);
  hipFuncSetAttribute((const void*)&gemm8_k<1>, hipFuncAttributeMaxDynamicSharedMemorySize, 131072);
  hipFuncSetAttribute((const void*)&gemm8_k<2>, hipFuncAttributeMaxDynamicSharedMemorySize, 131072);
  hipFuncSetAttribute((const void*)&gemm8_k<3>, hipFuncAttributeMaxDynamicSharedMemorySize, 131072);

  dim3 b328(32, 8);
  wtrans_k<<<dim3(32, 96), b328, 0, stream>>>(qkv_w, wq_t, 1024, 3072);
  wtrans_k<<<dim3(32, 32), b328, 0, stream>>>(proj_w, wp_t, 1024, 1024);
  wtrans_k<<<dim3(32, 128), b328, 0, stream>>>(fc1w, w1_t, 1024, 4096);
  wtrans_k<<<dim3(128, 32), b328, 0, stream>>>(fc2w, w2_t, 4096, 1024);

  ln_k<<<ROWS, 256, 0, stream>>>(x, n1w, n1b, hbuf);
  gemm8_k<0><<<dim3(36, 12), 512, 131072, stream>>>(hbuf, wq_t, qkv_b, nullptr, qkvb, 3072, 1024, 1024);

  gatherk_k<<<dim3(208, 256), 256, 0, stream>>>(qkvb, cache_k, kg);
  gathervt_k<<<dim3(26, 2, 256), b328, 0, stream>>>(qkvb, cache_v, vt);
  attn_k<<<dim3(9, 256), 256, 0, stream>>>(qkvb, kg, vt, obuf);

  gemm8_k<2><<<dim3(36, 4), 512, 131072, stream>>>(obuf, wp_t, proj_b, x, x2, 1024, 1024, 1024);
  ln_k<<<ROWS, 256, 0, stream>>>(x2, n2w, n2b, hbuf);
  gemm8_k<1><<<dim3(36, 16), 512, 131072, stream>>>(hbuf, w1_t, fc1b, nullptr, midb, 4096, 1024, 1024);

  // fc2: out = x2 + fc2_b + midb @ fc2_w  (split-K=4, atomic accumulate)
  initout_k<<<ROWS, 256, 0, stream>>>(x2, fc2b, (float*)d_out);
  gemm8_k<3><<<dim3(36, 4, 4), 512, 131072, stream>>>(midb, w2_t, nullptr, nullptr, (float*)d_out, 1024, 4096, 1024);
}

// Round 6
// 653.545 us; speedup vs baseline: 1.1882x; 1.1882x over previous
//
#include <hip/hip_runtime.h>

// Problem constants
#define Bb 16
#define Nn_ 576
#define Cc 1024
#define Hh 16
#define HD 64
#define HID 4096
#define AVAIL 832   // CUR(256) + N(576)
#define ROWS (Bb*Nn_)  // 9216

typedef __bf16 bf16x8 __attribute__((ext_vector_type(8)));
typedef float f32x4 __attribute__((ext_vector_type(4)));

__device__ __forceinline__ unsigned short f2bf(float f) {
  unsigned u = __float_as_uint(f);
  u += 0x7FFF + ((u >> 16) & 1);
  return (unsigned short)(u >> 16);
}

__device__ __forceinline__ void glds16(const void* g, void* l) {
  __builtin_amdgcn_global_load_lds(
      (const __attribute__((address_space(1))) void*)g,
      (__attribute__((address_space(3))) void*)l, 16, 0, 0);
}

#define BARR() asm volatile("s_barrier" ::: "memory")
#define VMCNT4() asm volatile("s_waitcnt vmcnt(4)" ::: "memory")
#define VMCNT0() asm volatile("s_waitcnt vmcnt(0)" ::: "memory")
#define LGKM0() asm volatile("s_waitcnt lgkmcnt(0)" ::: "memory")

// ---------------- weight convert + transpose: in [K][N] f32 -> out [N][K] bf16
__global__ void wtrans_k(const float* __restrict__ in, unsigned short* __restrict__ out,
                         int K, int N) {
  __shared__ float tile[32][33];
  int k0 = blockIdx.x * 32, n0 = blockIdx.y * 32;
  int tx = threadIdx.x, ty = threadIdx.y;  // 32 x 8
#pragma unroll
  for (int i = 0; i < 4; i++)
    tile[ty + i * 8][tx] = in[(size_t)(k0 + ty + i * 8) * N + n0 + tx];
  __syncthreads();
#pragma unroll
  for (int i = 0; i < 4; i++)
    out[(size_t)(n0 + ty + i * 8) * K + k0 + tx] = f2bf(tile[tx][ty + i * 8]);
}

// ---------------- LayerNorm f32 -> bf16, one block per row of 1024
__global__ void ln_k(const float* __restrict__ x, const float* __restrict__ w,
                     const float* __restrict__ bi, unsigned short* __restrict__ out) {
  int row = blockIdx.x;
  int t = threadIdx.x;
  float4 v = ((const float4*)(x + (size_t)row * Cc))[t];
  float s = v.x + v.y + v.z + v.w;
  float s2 = v.x * v.x + v.y * v.y + v.z * v.z + v.w * v.w;
#pragma unroll
  for (int off = 1; off < 64; off <<= 1) { s += __shfl_xor(s, off); s2 += __shfl_xor(s2, off); }
  __shared__ float red[8];
  int wid = t >> 6, lane = t & 63;
  if (lane == 0) { red[wid] = s; red[4 + wid] = s2; }
  __syncthreads();
  s = red[0] + red[1] + red[2] + red[3];
  s2 = red[4] + red[5] + red[6] + red[7];
  float mean = s * (1.0f / Cc);
  float var = s2 * (1.0f / Cc) - mean * mean;
  float rstd = rsqrtf(var + 1e-5f);
  float4 wv = ((const float4*)w)[t];
  float4 bv = ((const float4*)bi)[t];
  ushort4 ov;
  ov.x = f2bf((v.x - mean) * rstd * wv.x + bv.x);
  ov.y = f2bf((v.y - mean) * rstd * wv.y + bv.y);
  ov.z = f2bf((v.z - mean) * rstd * wv.z + bv.z);
  ov.w = f2bf((v.w - mean) * rstd * wv.w + bv.w);
  *(ushort4*)(out + (size_t)row * Cc + t * 4) = ov;
}

// ---------------- 256x256 8-wave pipelined GEMM, BK=64, 128KB LDS dbuf.
// C[M][N] = A[M][K](bf16) @ Bt[N][K]^T (bf16) + bias
// EPI: 0 bf16, 1 gelu->bf16, 2 f32+resid
// Epilogue goes through per-wave LDS scratch so global stores are 256B
// coalesced full-line writes (fixes write-allocate over-fetch: scalar 2B/4B
// stores were pulling the whole output region in from HBM).
template <int EPI>
__global__ __launch_bounds__(512, 2) void gemm8_k(
    const unsigned short* __restrict__ A, const unsigned short* __restrict__ Bt,
    const float* __restrict__ bias, const float* __restrict__ resid,
    void* __restrict__ outv, int N, int K) {
  extern __shared__ __align__(16) char smem[];
  char* A0buf = smem;            // buf0 A tile (2 halves of 16KB)
  char* B0buf = smem + 32768;    // buf0 B tile
  char* A1buf = smem + 65536;    // buf1 A tile
  char* B1buf = smem + 98304;    // buf1 B tile

  const int tid = threadIdx.x, lane = tid & 63, wid = tid >> 6;
  const int wr = wid >> 2, wc = wid & 3;
  const int l15 = lane & 15, l4 = lane >> 4;
  const int m0 = blockIdx.x * 256, n0 = blockIdx.y * 256;
  const int KT = K >> 6;
  const size_t K2 = (size_t)K * 2;

  // staging: thread covers row (tid>>3) of a 64-row stripe, 16B slot (tid&7)^((tid>>3)&7)
  const int toff = (tid >> 3) * (int)K2 + ((((tid & 7) ^ ((tid >> 3) & 7)) << 4));
  const char* As0 = (const char*)A + (size_t)m0 * K2 + toff;         // A rows m0..
  const char* As1 = As0 + 128 * K2;                                  // A rows m0+128..
  const char* Bs0 = (const char*)Bt + (size_t)n0 * K2 + toff;
  const char* Bs1 = Bs0 + 128 * K2;
  const size_t l64 = 64 * K2;
  const int dst = tid * 16;

  // read-side: swizzled 16B-slot offset for ks=0; ks=1 flips byte bit6
  const int s0 = ((l4 ^ (l15 & 7)) << 4);
  const int rbA = (wr * 128 + l15) * 128;
  const int rbB = (wc * 64 + l15) * 128;

  f32x4 acc[2][2][4][2] = {};  // [mh][nh][mi][ni]
  bf16x8 a0[4][2], a1[4][2], bb0[2][2], bb1[2][2];

#define STAGE(srcH, ktb, ldsT, half)                        \
  do {                                                      \
    const char* _g = (srcH) + (size_t)(ktb);                \
    glds16(_g, (ldsT) + (half) * 16384 + dst);              \
    glds16(_g + l64, (ldsT) + (half) * 16384 + 8192 + dst); \
  } while (0)

#define RD_A(dA, CA, mh)                                                           \
  _Pragma("unroll") for (int mi = 0; mi < 4; ++mi)                                 \
  _Pragma("unroll") for (int ks = 0; ks < 2; ++ks)                                 \
    dA[mi][ks] = *(const bf16x8*)((CA) + rbA + (mh) * 8192 + mi * 2048 + (s0 ^ (ks << 6)));

#define RD_B(dB, CB, nh)                                                           \
  _Pragma("unroll") for (int ni = 0; ni < 2; ++ni)                                 \
  _Pragma("unroll") for (int ks = 0; ks < 2; ++ks)                                 \
    dB[ni][ks] = *(const bf16x8*)((CB) + rbB + (nh) * 4096 + ni * 2048 + (s0 ^ (ks << 6)));

#define MF(mh, nh, av, bv)                                                         \
  _Pragma("unroll") for (int mi = 0; mi < 4; ++mi)                                 \
  _Pragma("unroll") for (int ni = 0; ni < 2; ++ni)                                 \
  _Pragma("unroll") for (int ks = 0; ks < 2; ++ks)                                 \
    acc[mh][nh][mi][ni] = __builtin_amdgcn_mfma_f32_16x16x32_bf16(                 \
        av[mi][ks], bv[ni][ks], acc[mh][nh][mi][ni], 0, 0, 0);

// Steady-state K-tile, reads balanced per quadrant (12/4/8/0):
#define TILE(CA, CB, OA, OB, t)                                     \
  do {                                                              \
    const size_t kt1 = (size_t)((t) + 1) * 128;                     \
    const size_t kt2 = (size_t)((t) + 2) * 128;                     \
    /* P1 */                                                        \
    RD_A(a0, CA, 0); RD_B(bb0, CB, 0);                              \
    STAGE(As1, kt1, OA, 1);                                         \
    BARR();                                                         \
    __builtin_amdgcn_s_setprio(1); MF(0, 0, a0, bb0);               \
    __builtin_amdgcn_s_setprio(0); BARR();                          \
    /* P2 */                                                        \
    RD_B(bb1, CB, 1);                                               \
    STAGE(Bs1, kt1, OB, 1);                                         \
    BARR();                                                         \
    __builtin_amdgcn_s_setprio(1); MF(0, 1, a0, bb1);               \
    __builtin_amdgcn_s_setprio(0); BARR();                          \
    /* P3 */                                                        \
    RD_A(a1, CA, 1);                                                \
    LGKM0(); BARR();                                                \
    __builtin_amdgcn_s_setprio(1); MF(1, 0, a1, bb0);               \
    __builtin_amdgcn_s_setprio(0); BARR();                          \
    /* P4 */                                                        \
    STAGE(As0, kt2, CA, 0);                                         \
    STAGE(Bs0, kt2, CB, 0);                                         \
    VMCNT4(); BARR();                                               \
    __builtin_amdgcn_s_setprio(1); MF(1, 1, a1, bb1);               \
    __builtin_amdgcn_s_setprio(0); BARR();                          \
  } while (0)

// Tile KT-2: stage only tile KT-1 half1; drain ALL loads at P4.
#define TILE_T1(CA, CB, OA, OB, t)                                  \
  do {                                                              \
    const size_t kt1 = (size_t)((t) + 1) * 128;                     \
    RD_A(a0, CA, 0); RD_B(bb0, CB, 0);                              \
    STAGE(As1, kt1, OA, 1);                                         \
    BARR();                                                         \
    __builtin_amdgcn_s_setprio(1); MF(0, 0, a0, bb0);               \
    __builtin_amdgcn_s_setprio(0); BARR();                          \
    RD_B(bb1, CB, 1);                                               \
    STAGE(Bs1, kt1, OB, 1);                                         \
    BARR();                                                         \
    __builtin_amdgcn_s_setprio(1); MF(0, 1, a0, bb1);               \
    __builtin_amdgcn_s_setprio(0); BARR();                          \
    RD_A(a1, CA, 1);                                                \
    LGKM0(); BARR();                                                \
    __builtin_amdgcn_s_setprio(1); MF(1, 0, a1, bb0);               \
    __builtin_amdgcn_s_setprio(0); BARR();                          \
    VMCNT0(); BARR();                                               \
    __builtin_amdgcn_s_setprio(1); MF(1, 1, a1, bb1);               \
    __builtin_amdgcn_s_setprio(0); BARR();                          \
  } while (0)

// Tile KT-1: pure compute.
#define TILE_T2(CA, CB)                                             \
  do {                                                              \
    RD_A(a0, CA, 0); RD_A(a1, CA, 1); RD_B(bb0, CB, 0); RD_B(bb1, CB, 1); \
    MF(0, 0, a0, bb0); MF(0, 1, a0, bb1);                           \
    MF(1, 0, a1, bb0); MF(1, 1, a1, bb1);                           \
  } while (0)

  // prologue: stage tile0 (4 halves) + tile1 half0
  STAGE(As0, 0, A0buf, 0);
  STAGE(Bs0, 0, B0buf, 0);
  STAGE(As1, 0, A0buf, 1);
  STAGE(Bs1, 0, B0buf, 1);
  STAGE(As0, 128, A1buf, 0);
  STAGE(Bs0, 128, B1buf, 0);
  VMCNT4();
  BARR();

#pragma unroll 1
  for (int t = 0; t + 3 < KT; t += 2) {
    TILE(A0buf, B0buf, A1buf, B1buf, t);
    TILE(A1buf, B1buf, A0buf, B0buf, t + 1);
  }
  TILE_T1(A0buf, B0buf, A1buf, B1buf, KT - 2);
  TILE_T2(A1buf, B1buf);

  // ---- coalesced epilogue via per-wave LDS scratch ----
  BARR();  // all waves' LDS-tile reads are done; smem is reusable
  {
    float* eb = (float*)(smem + wid * 16384);  // private 16KB per wave
    const int gc0 = n0 + wc * 64;
    const f32x4 bv4 = *(const f32x4*)&bias[gc0 + l15 * 4];
#pragma unroll
    for (int mh = 0; mh < 2; mh++) {
#pragma unroll
      for (int mi = 0; mi < 4; mi++) {
        // scatter 16 rows x 64 cols (f32, row stride 68) into LDS
#pragma unroll
        for (int nh = 0; nh < 2; nh++)
#pragma unroll
          for (int ni = 0; ni < 2; ni++)
#pragma unroll
            for (int j = 0; j < 4; j++)
              eb[(l4 * 4 + j) * 68 + nh * 32 + ni * 16 + l15] = acc[mh][nh][mi][ni][j];
        int gr0 = m0 + wr * 128 + mh * 64 + mi * 16;
#pragma unroll
        for (int k = 0; k < 4; k++) {
          int r = k * 4 + l4;  // 0..15
          f32x4 v = *(const f32x4*)&eb[r * 68 + l15 * 4];
          v += bv4;
          size_t base = (size_t)(gr0 + r) * N + gc0 + l15 * 4;
          if (EPI == 1) {
#pragma unroll
            for (int q = 0; q < 4; q++)
              v[q] = 0.5f * v[q] * (1.0f + erff(v[q] * 0.70710678118f));
          }
          if (EPI == 2) {
            f32x4 rv = *(const f32x4*)&resid[base];
            *(f32x4*)((float*)outv + base) = v + rv;
          } else {
            ushort4 o4;
            o4.x = f2bf(v[0]); o4.y = f2bf(v[1]); o4.z = f2bf(v[2]); o4.w = f2bf(v[3]);
            *(ushort4*)((unsigned short*)outv + base) = o4;
          }
        }
      }
    }
  }
#undef TILE_T2
#undef TILE_T1
#undef TILE
#undef MF
#undef RD_B
#undef RD_A
#undef STAGE
}

// ---------------- gather K: Kg[bh][p][d] (bf16) from qkv + cache_k
__global__ void gatherk_k(const unsigned short* __restrict__ qkv,
                          const float* __restrict__ cache_k,
                          unsigned short* __restrict__ Kg) {
  int bh = blockIdx.y, b = bh >> 4, h = bh & 15;
  int p = blockIdx.x * 4 + (threadIdx.x >> 6);
  int d = threadIdx.x & 63;
  unsigned short val;
  if (p < 64)
    val = qkv[((size_t)(b * Nn_ + p)) * 3072 + 1024 + h * 64 + d];
  else if (p < 320)
    val = f2bf(cache_k[(((size_t)b * Hh + h) * 1024 + p) * 64 + d]);
  else
    val = qkv[((size_t)(b * Nn_ + p - 256)) * 3072 + 1024 + h * 64 + d];
  Kg[(((size_t)bh) * AVAIL + p) * 64 + d] = val;
}

// ---------------- gather V transposed: Vt[bh][d][p] (bf16)
__global__ void gathervt_k(const unsigned short* __restrict__ qkv,
                           const float* __restrict__ cache_v,
                           unsigned short* __restrict__ Vt) {
  __shared__ float tile[32][33];
  int bh = blockIdx.z, b = bh >> 4, h = bh & 15;
  int p0 = blockIdx.x * 32, d0 = blockIdx.y * 32;
  int tx = threadIdx.x, ty = threadIdx.y;  // 32 x 8
#pragma unroll
  for (int i = 0; i < 4; i++) {
    int p = p0 + ty + i * 8, d = d0 + tx;
    float v;
    if (p < 64)
      v = __uint_as_float((unsigned)qkv[((size_t)(b * Nn_ + p)) * 3072 + 2048 + h * 64 + d] << 16);
    else if (p < 320)
      v = cache_v[(((size_t)b * Hh + h) * 1024 + p) * 64 + d];
    else
      v = __uint_as_float((unsigned)qkv[((size_t)(b * Nn_ + p - 256)) * 3072 + 2048 + h * 64 + d] << 16);
    tile[ty + i * 8][tx] = v;
  }
  __syncthreads();
#pragma unroll
  for (int i = 0; i < 4; i++)
    Vt[(((size_t)bh) * 64 + d0 + ty + i * 8) * AVAIL + p0 + tx] = f2bf(tile[tx][ty + i * 8]);
}

// ---------------- flash attention: block = (qtile, bh); 4 waves x 16 q-rows
__global__ __launch_bounds__(256) void attn_k(
    const unsigned short* __restrict__ qkv, const unsigned short* __restrict__ Kg,
    const unsigned short* __restrict__ Vt, unsigned short* __restrict__ o) {
  __shared__ __attribute__((aligned(16))) unsigned short Qs[64 * 64];
  __shared__ __attribute__((aligned(16))) unsigned short Ks[64 * 64];
  __shared__ __attribute__((aligned(16))) unsigned short Vs[64 * 64];
  __shared__ __attribute__((aligned(16))) unsigned short Ps[4][16 * 64];

  const int tid = threadIdx.x;
  const int lane = tid & 63;
  const int w = tid >> 6;
  const int qt = blockIdx.x;
  const int bh = blockIdx.y, b = bh >> 4, h = bh & 15;
  const float scale = 0.125f;

  {
    int r = tid >> 3;
    int cb = (tid & 7) << 4;
    const char* qb = (const char*)qkv;
    glds16(qb + ((size_t)(b * Nn_ + qt * 64 + r) * 3072 + h * 64) * 2 + cb, (char*)Qs + tid * 16);
    glds16(qb + ((size_t)(b * Nn_ + qt * 64 + 32 + r) * 3072 + h * 64) * 2 + cb,
           (char*)Qs + 4096 + tid * 16);
  }

  float m_run[4], l_run[4];
  f32x4 oacc[4] = {};
#pragma unroll
  for (int j = 0; j < 4; j++) { m_run[j] = -1e30f; l_run[j] = 0.f; }

  const char* kbase = (const char*)(Kg + (size_t)bh * AVAIL * 64);
  const char* vbase = (const char*)(Vt + (size_t)bh * 64 * AVAIL);

  for (int c = 0; c < 13; c++) {
    __syncthreads();
    glds16(kbase + (size_t)c * 8192 + tid * 16, (char*)Ks + tid * 16);
    glds16(kbase + (size_t)c * 8192 + 4096 + tid * 16, (char*)Ks + 4096 + tid * 16);
    {
      int r = tid >> 3;
      int cb = (tid & 7) << 4;
      glds16(vbase + (size_t)r * (AVAIL * 2) + c * 128 + cb, (char*)Vs + tid * 16);
      glds16(vbase + (size_t)(r + 32) * (AVAIL * 2) + c * 128 + cb, (char*)Vs + 4096 + tid * 16);
    }
    asm volatile("s_waitcnt vmcnt(0)" ::: "memory");
    __syncthreads();

    bf16x8 qf[2];
#pragma unroll
    for (int t = 0; t < 2; t++)
      qf[t] = *(const bf16x8*)&Qs[(w * 16 + (lane & 15)) * 64 + t * 32 + (lane >> 4) * 8];
    f32x4 s[4] = {};
#pragma unroll
    for (int nt = 0; nt < 4; nt++) {
#pragma unroll
      for (int t = 0; t < 2; t++) {
        bf16x8 kf = *(const bf16x8*)&Ks[(nt * 16 + (lane & 15)) * 64 + t * 32 + (lane >> 4) * 8];
        s[nt] = __builtin_amdgcn_mfma_f32_16x16x32_bf16(qf[t], kf, s[nt], 0, 0, 0);
      }
    }

    float p[4][4];
#pragma unroll
    for (int j = 0; j < 4; j++) {
      float mx = fmaxf(fmaxf(s[0][j], s[1][j]), fmaxf(s[2][j], s[3][j])) * scale;
#pragma unroll
      for (int off = 1; off < 16; off <<= 1) mx = fmaxf(mx, __shfl_xor(mx, off));
      float m_new = fmaxf(m_run[j], mx);
      float alpha = __expf(m_run[j] - m_new);
      float sum = 0.f;
#pragma unroll
      for (int nt = 0; nt < 4; nt++) {
        p[nt][j] = __expf(s[nt][j] * scale - m_new);
        sum += p[nt][j];
      }
#pragma unroll
      for (int off = 1; off < 16; off <<= 1) sum += __shfl_xor(sum, off);
      l_run[j] = l_run[j] * alpha + sum;
      m_run[j] = m_new;
#pragma unroll
      for (int nt2 = 0; nt2 < 4; nt2++) oacc[nt2][j] *= alpha;
    }

#pragma unroll
    for (int nt = 0; nt < 4; nt++)
#pragma unroll
      for (int j = 0; j < 4; j++)
        Ps[w][((lane >> 4) * 4 + j) * 64 + nt * 16 + (lane & 15)] = f2bf(p[nt][j]);

    bf16x8 pa[2];
#pragma unroll
    for (int t = 0; t < 2; t++)
      pa[t] = *(const bf16x8*)&Ps[w][(lane & 15) * 64 + t * 32 + (lane >> 4) * 8];
#pragma unroll
    for (int nt2 = 0; nt2 < 4; nt2++) {
#pragma unroll
      for (int t = 0; t < 2; t++) {
        bf16x8 vf = *(const bf16x8*)&Vs[(nt2 * 16 + (lane & 15)) * 64 + t * 32 + (lane >> 4) * 8];
        oacc[nt2] = __builtin_amdgcn_mfma_f32_16x16x32_bf16(pa[t], vf, oacc[nt2], 0, 0, 0);
      }
    }
  }

#pragma unroll
  for (int nt2 = 0; nt2 < 4; nt2++) {
#pragma unroll
    for (int j = 0; j < 4; j++) {
      int q = qt * 64 + w * 16 + (lane >> 4) * 4 + j;
      float v = oacc[nt2][j] / l_run[j];
      o[((size_t)(b * Nn_ + q)) * Cc + h * 64 + nt2 * 16 + (lane & 15)] = f2bf(v);
    }
  }
}

extern "C" void kernel_launch(void* const* d_in, const int* in_sizes, int n_in,
                              void* d_out, int out_size, void* d_ws, size_t ws_size,
                              hipStream_t stream) {
  const float* x = (const float*)d_in[0];
  const float* cache_k = (const float*)d_in[1];
  const float* cache_v = (const float*)d_in[2];
  const float* qkv_w = (const float*)d_in[3];
  const float* qkv_b = (const float*)d_in[4];
  const float* proj_w = (const float*)d_in[5];
  const float* proj_b = (const float*)d_in[6];
  const float* n1w = (const float*)d_in[7];
  const float* n1b = (const float*)d_in[8];
  const float* n2w = (const float*)d_in[9];
  const float* n2b = (const float*)d_in[10];
  const float* fc1w = (const float*)d_in[11];
  const float* fc1b = (const float*)d_in[12];
  const float* fc2w = (const float*)d_in[13];
  const float* fc2b = (const float*)d_in[14];

  char* ws = (char*)d_ws;
  unsigned short* wq_t = (unsigned short*)(ws + 0);          //  [3072][1024]
  unsigned short* wp_t = (unsigned short*)(ws + 6291456);    //  [1024][1024]
  unsigned short* w1_t = (unsigned short*)(ws + 8388608);    //  [4096][1024]
  unsigned short* w2_t = (unsigned short*)(ws + 16777216);   //  [1024][4096]
  float* x2           = (float*)(ws + 25165824);             //  [9216][1024] f32
  unsigned short* obuf = (unsigned short*)(ws + 62914560);   //  [9216][1024]
  unsigned short* hbuf = (unsigned short*)(ws + 81788928);   //  [9216][1024]
  unsigned short* vt   = (unsigned short*)(ws + 100663296);  //  [256][64][832]
  unsigned short* qkvb = (unsigned short*)(ws + 127926272);  //  [9216][3072]
  unsigned short* kg   = (unsigned short*)(ws + 184549376);  //  [256][832][64]
  unsigned short* midb = qkvb;  // fc1 out [9216][4096]; overruns into kg (dead by then)

  // allow 128KB dynamic LDS for gemm8 instantiations
  hipFuncSetAttribute((const void*)&gemm8_k<0>, hipFuncAttributeMaxDynamicSharedMemorySize, 131072);
  hipFuncSetAttribute((const void*)&gemm8_k<1>, hipFuncAttributeMaxDynamicSharedMemorySize, 131072);
  hipFuncSetAttribute((const void*)&gemm8_k<2>, hipFuncAttributeMaxDynamicSharedMemorySize, 131072);

  dim3 b328(32, 8);
  wtrans_k<<<dim3(32, 96), b328, 0, stream>>>(qkv_w, wq_t, 1024, 3072);
  wtrans_k<<<dim3(32, 32), b328, 0, stream>>>(proj_w, wp_t, 1024, 1024);
  wtrans_k<<<dim3(32, 128), b328, 0, stream>>>(fc1w, w1_t, 1024, 4096);
  wtrans_k<<<dim3(128, 32), b328, 0, stream>>>(fc2w, w2_t, 4096, 1024);

  ln_k<<<ROWS, 256, 0, stream>>>(x, n1w, n1b, hbuf);
  gemm8_k<0><<<dim3(36, 12), 512, 131072, stream>>>(hbuf, wq_t, qkv_b, nullptr, qkvb, 3072, 1024);

  gatherk_k<<<dim3(208, 256), 256, 0, stream>>>(qkvb, cache_k, kg);
  gathervt_k<<<dim3(26, 2, 256), b328, 0, stream>>>(qkvb, cache_v, vt);
  attn_k<<<dim3(9, 256), 256, 0, stream>>>(qkvb, kg, vt, obuf);

  gemm8_k<2><<<dim3(36, 4), 512, 131072, stream>>>(obuf, wp_t, proj_b, x, x2, 1024, 1024);
  ln_k<<<ROWS, 256, 0, stream>>>(x2, n2w, n2b, hbuf);
  gemm8_k<1><<<dim3(36, 16), 512, 131072, stream>>>(hbuf, w1_t, fc1b, nullptr, midb, 4096, 1024);
  gemm8_k<2><<<dim3(36, 4), 512, 131072, stream>>>(midb, w2_t, fc2b, x2, (float*)d_out, 1024, 4096);
}